// Round 9
// baseline (921.711 us; speedup 1.0000x reference)
//
#include <hip/hip_runtime.h>

#define Nn   50000
#define Ee   400000
#define Ff   512
#define H1   1024
#define H2   512
#define Bb   50
#define OUTd 10
#define EPSc 1e-5f
#define NPg  1000   // nodes per graph
#define EPg  8000   // edges per graph

typedef _Float16 h8 __attribute__((ext_vector_type(8)));
typedef _Float16 h4 __attribute__((ext_vector_type(4)));
typedef float f4 __attribute__((ext_vector_type(4)));

// ---------- monotone float<->uint mapping for atomicMax on floats ----------
__device__ __forceinline__ unsigned fmap(float f) {
    unsigned u = __float_as_uint(f);
    return (u & 0x80000000u) ? ~u : (u | 0x80000000u);
}
__device__ __forceinline__ float funmap(unsigned m) {
    unsigned u = (m & 0x80000000u) ? (m ^ 0x80000000u) : ~m;
    return __uint_as_float(u);
}

__device__ __forceinline__ void gl_lds16(const void* g, void* l) {
    __builtin_amdgcn_global_load_lds(
        (const __attribute__((address_space(1))) unsigned int*)g,
        (__attribute__((address_space(3))) unsigned int*)l,
        16, 0, 0);
}

// ---------- init: zero all accumulators (ws is poisoned 0xAA once) ----------
__global__ void init_kernel(unsigned* maxu, double* den,
                            double* cs1, double* css1, double* cs2, double* css2,
                            float* pool, float* cnt, int* scal) {
    int i = blockIdx.x * blockDim.x + threadIdx.x;
    int nth = gridDim.x * blockDim.x;
    for (int n = i; n < Nn; n += nth) { maxu[n] = 0u; den[n] = 0.0; }
    for (int j = i; j < H1; j += nth) { cs1[j] = 0.0; css1[j] = 0.0; }
    for (int j = i; j < H2; j += nth) { cs2[j] = 0.0; css2[j] = 0.0; }
    for (int j = i; j < Bb * H2; j += nth) pool[j] = 0.f;
    for (int j = i; j < Bb; j += nth) cnt[j] = 0.f;
    if (i < 16) scal[i] = 0;
}

// ---------- f32 -> f16 hi/lo split (compensated) ----------
__global__ void split_pair_kernel(const float* __restrict__ in, _Float16* __restrict__ hi,
                                  _Float16* __restrict__ lo, int n4) {
    int i = blockIdx.x * blockDim.x + threadIdx.x;
    int nth = gridDim.x * blockDim.x;
    for (; i < n4; i += nth) {
        float4 v = ((const float4*)in)[i];
        h4 H = { (_Float16)v.x, (_Float16)v.y, (_Float16)v.z, (_Float16)v.w };
        h4 L = { (_Float16)(v.x - (float)H[0]), (_Float16)(v.y - (float)H[1]),
                 (_Float16)(v.z - (float)H[2]), (_Float16)(v.w - (float)H[3]) };
        ((h4*)hi)[i] = H;
        ((h4*)lo)[i] = L;
    }
}
// ---------- f32 -> f16 single ----------
__global__ void tof16_kernel(const float* __restrict__ in, _Float16* __restrict__ out, int n4) {
    int i = blockIdx.x * blockDim.x + threadIdx.x;
    int nth = gridDim.x * blockDim.x;
    for (; i < n4; i += nth) {
        float4 v = ((const float4*)in)[i];
        h4 H = { (_Float16)v.x, (_Float16)v.y, (_Float16)v.z, (_Float16)v.w };
        ((h4*)out)[i] = H;
    }
}

// ---------- MFMA GEMM: C[m][n] = sum_k A[m][k]*B[n][k] + bias[n], fused col-stats ----------
// SPLIT: C = Ahi*Bhi + Ahi*Blo + Alo*Bhi (fp32-equivalent accuracy)
// 128x128 tile, BK=32, 4 waves. Pipeline (T4 counted vmcnt, raw s_barrier):
//   A arrays 3-deep (staged 2 K-steps ahead, covers ~900cy HBM latency),
//   B arrays 2-deep (L2-hot weights, ~200cy).
//   per iter i: [A-waves vmcnt(LPS) | B-waves vmcnt(0)] ; s_barrier ;
//               STAGE_A(i+2) ; STAGE_B(i+1) ; ds_read+MFMA(buf i)
// vmcnt ledger (per A-wave): before wait at iter i outstanding = {tile i, tile i+1};
// vmcnt(LPS) retires tile i exactly. WAR-safe: buffer (i+2)%3 was last read at
// iter i-1, strictly before the iter-i barrier.
// Grid: 1D n-fastest + bijective XCD-chunk swizzle (m204).
template<int KD, bool SPLIT>
__global__ __launch_bounds__(256) void gemm_mfma_kernel(
        const _Float16* __restrict__ Ahi, const _Float16* __restrict__ Alo,
        const _Float16* __restrict__ Bhi, const _Float16* __restrict__ Blo,
        const float* __restrict__ bias, float* __restrict__ C, int Nc,
        int Mconst, const int* __restrict__ Mptr, int nT,
        double* __restrict__ csum, double* __restrict__ cssum)
{
    const int M = Mptr ? Mptr[0] : Mconst;
    // XCD-chunk bijective remap (nwg need not be %8==0)
    const int nwg = gridDim.x, orig = blockIdx.x;
    const int qq = nwg >> 3, rr = nwg & 7;
    const int xcd = orig & 7, idx = orig >> 3;
    const int lin = (xcd < rr ? xcd * (qq + 1) : rr * (qq + 1) + (xcd - rr) * qq) + idx;
    const int bmI = lin / nT;
    const int bm = bmI * 128, bn = (lin - bmI * nT) * 128;
    if (bm >= M) return;
    constexpr int NK = KD / 32;
    constexpr int LPS = SPLIT ? 8 : 4;     // gl_lds16 per wave per stage
    __shared__ __align__(16) _Float16 sAh[3 * 4096];
    __shared__ __align__(16) _Float16 sAl[SPLIT ? 3 * 4096 : 8];
    __shared__ __align__(16) _Float16 sBh[2 * 4096];
    __shared__ __align__(16) _Float16 sBl[SPLIT ? 2 * 4096 : 8];
    const int tid = threadIdx.x, lane = tid & 63, wave = tid >> 6;
    const int rIn = lane >> 2;                                    // staging row-in-chunk
    const int kSrcByte = ((((lane & 3) - ((lane >> 3) & 3)) & 3) << 4);  // swizzled source granule
    const int wr = wave >> 1, wc = wave & 1;                      // wave grid 2x2
    const int lr = lane & 15, kb = lane >> 4;                     // fragment lane decomposition
    const int pGr = ((kb + ((lr >> 1) & 3)) & 3) << 3;            // read granule (f16 elems)
    const bool isAwave = (wave < 2);
    f4 acc[4][4] = {};

    auto STAGE_A = [&](int b, int k0) {
        if (!isAwave) return;
        if (SPLIT) {
            const _Float16* gp = wave ? Alo : Ahi;
            _Float16* lp = (wave ? sAl : sAh) + b * 4096;
#pragma unroll
            for (int c = 0; c < 8; ++c) {
                int row = min(bm + c * 16 + rIn, M - 1);
                gl_lds16((const char*)gp + ((size_t)row * KD + k0) * 2 + kSrcByte, lp + c * 512);
            }
        } else {
            _Float16* lp = sAh + b * 4096;
            const int hf = wave & 1;
#pragma unroll
            for (int c2 = 0; c2 < 4; ++c2) {
                int c = hf * 4 + c2;
                int row = min(bm + c * 16 + rIn, M - 1);
                gl_lds16((const char*)Ahi + ((size_t)row * KD + k0) * 2 + kSrcByte, lp + c * 512);
            }
        }
    };
    auto STAGE_B = [&](int b, int k0) {
        if (isAwave) return;
        if (SPLIT) {
            const _Float16* gp = (wave == 3) ? Blo : Bhi;
            _Float16* lp = ((wave == 3) ? sBl : sBh) + b * 4096;
#pragma unroll
            for (int c = 0; c < 8; ++c) {
                int row = bn + c * 16 + rIn;
                gl_lds16((const char*)gp + ((size_t)row * KD + k0) * 2 + kSrcByte, lp + c * 512);
            }
        } else {
            _Float16* lp = sBh + b * 4096;
            const int hf = wave & 1;
#pragma unroll
            for (int c2 = 0; c2 < 4; ++c2) {
                int c = hf * 4 + c2;
                int row = bn + c * 16 + rIn;
                gl_lds16((const char*)Bhi + ((size_t)row * KD + k0) * 2 + kSrcByte, lp + c * 512);
            }
        }
    };

    // prologue: A 2 tiles ahead, B 1 tile ahead
    STAGE_A(0, 0);
    STAGE_A(1, 32);
    STAGE_B(0, 0);

    int a3 = 0, b2 = 0;     // i%3, i%2 trackers
    for (int i = 0; i < NK; ++i) {
        // counted wait: A-waves leave next A-stage in flight; B-waves drain
        if (isAwave && (i + 1 < NK)) {
            asm volatile("s_waitcnt vmcnt(%0)" :: "i"(LPS) : "memory");
        } else {
            asm volatile("s_waitcnt vmcnt(0)" ::: "memory");
        }
        __builtin_amdgcn_sched_barrier(0);
        __builtin_amdgcn_s_barrier();
        __builtin_amdgcn_sched_barrier(0);
        // stage after barrier (prior-step reads proven complete -> WAR-safe)
        if (i + 2 < NK) { int nb = (i + 2) % 3; STAGE_A(nb, (i + 2) * 32); }
        if (i + 1 < NK) { int nb = (i + 1) & 1; STAGE_B(nb, (i + 1) * 32); }
        __builtin_amdgcn_sched_barrier(0);
        // ---- compute on buf (a3, b2) ----
        const _Float16* AhP = sAh + a3 * 4096;
        const _Float16* AlP = SPLIT ? sAl + a3 * 4096 : nullptr;
        const _Float16* BhP = sBh + b2 * 4096;
        const _Float16* BlP = SPLIT ? sBl + b2 * 4096 : nullptr;
        const int ar = (wr * 64 + lr) * 32 + pGr;
        const int br = (wc * 64 + lr) * 32 + pGr;
        h8 ahf[4], bhf[4], alf[4], blf[4];
#pragma unroll
        for (int j = 0; j < 4; ++j) {
            ahf[j] = *(const h8*)&AhP[ar + j * 512];
            bhf[j] = *(const h8*)&BhP[br + j * 512];
            if (SPLIT) {
                alf[j] = *(const h8*)&AlP[ar + j * 512];
                blf[j] = *(const h8*)&BlP[br + j * 512];
            }
        }
#pragma unroll
        for (int mi = 0; mi < 4; ++mi)
#pragma unroll
            for (int ni = 0; ni < 4; ++ni) {
                acc[mi][ni] = __builtin_amdgcn_mfma_f32_16x16x32_f16(ahf[mi], bhf[ni], acc[mi][ni], 0, 0, 0);
                if (SPLIT) {
                    acc[mi][ni] = __builtin_amdgcn_mfma_f32_16x16x32_f16(ahf[mi], blf[ni], acc[mi][ni], 0, 0, 0);
                    acc[mi][ni] = __builtin_amdgcn_mfma_f32_16x16x32_f16(alf[mi], bhf[ni], acc[mi][ni], 0, 0, 0);
                }
            }
        a3 = (a3 == 2) ? 0 : a3 + 1;
        b2 ^= 1;
    }
    // ---- epilogue: bias, store, fused column stats (sum & sumsq over valid rows) ----
    // C/D layout (m89-verified): col = lane&15, row = (lane>>4)*4 + reg_idx
#pragma unroll
    for (int ni = 0; ni < 4; ++ni) {
        const int col = bn + wc * 64 + ni * 16 + lr;
        const float bv = bias[col];
        double sd_ = 0.0, ssd = 0.0;
#pragma unroll
        for (int mi = 0; mi < 4; ++mi)
#pragma unroll
            for (int r = 0; r < 4; ++r) {
                int row = bm + wr * 64 + mi * 16 + kb * 4 + r;
                if (row < M) {
                    float v = acc[mi][ni][r] + bv;
                    C[(size_t)row * Nc + col] = v;
                    sd_ += (double)v;
                    ssd += (double)v * (double)v;
                }
            }
        // reduce over kb (lanes 16 apart share the same col)
        sd_ += __shfl_xor(sd_, 16); ssd += __shfl_xor(ssd, 16);
        sd_ += __shfl_xor(sd_, 32); ssd += __shfl_xor(ssd, 32);
        if (kb == 0) {
            atomicAdd(&csum[col], sd_);
            atomicAdd(&cssum[col], ssd);
        }
    }
}

// ---------- BN params: a = g/sqrt(var+eps), bb = be - mean*a ----------
__global__ void bnparam_kernel(const double* __restrict__ s, const double* __restrict__ ss,
                               const float* __restrict__ g, const float* __restrict__ be,
                               float* __restrict__ a, float* __restrict__ bb, int cols,
                               const float* __restrict__ padBias, const int* __restrict__ CvPtr) {
    int j = blockIdx.x * blockDim.x + threadIdx.x;
    if (j >= cols) return;
    double sum = s[j], sumsq = ss[j];
    if (CvPtr) {  // padding rows equal to bias (zero input rows @ W + b)
        double pad = (double)(Nn - CvPtr[0]);
        double bv = padBias ? (double)padBias[j] : 0.0;
        sum += pad * bv; sumsq += pad * bv * bv;
    }
    double mean = sum / (double)Nn;
    double var = sumsq / (double)Nn - mean * mean;
    float aj = g[j] / sqrtf((float)var + EPSc);
    a[j] = aj;
    bb[j] = be[j] - (float)mean * aj;
}

// ---------- p,q row dots over BN+ReLU(h), NO h write-back; one WAVE per node ----------
__global__ __launch_bounds__(256) void pq_kernel(const float* __restrict__ h,
        const float* __restrict__ a, const float* __restrict__ bb,
        const float* __restrict__ Wp, float* __restrict__ p, float* __restrict__ q) {
    const int n = blockIdx.x * 4 + (threadIdx.x >> 6);
    if (n >= Nn) return;
    const int lane = threadIdx.x & 63;
    float sp = 0.f, sq = 0.f;
    const float* row = h + (size_t)n * H1;
#pragma unroll
    for (int u = 0; u < 4; ++u) {
        int j = u * 256 + lane * 4;
        float4 v = *(const float4*)(row + j);
        const float4 av = *(const float4*)(a + j);
        const float4 bv = *(const float4*)(bb + j);
        v.x = fmaxf(v.x * av.x + bv.x, 0.f);
        v.y = fmaxf(v.y * av.y + bv.y, 0.f);
        v.z = fmaxf(v.z * av.z + bv.z, 0.f);
        v.w = fmaxf(v.w * av.w + bv.w, 0.f);
        const float4 wp = *(const float4*)(Wp + j);
        const float4 wq = *(const float4*)(Wp + H1 + j);
        sp += v.x * wp.x + v.y * wp.y + v.z * wp.z + v.w * wp.w;
        sq += v.x * wq.x + v.y * wq.y + v.z * wq.z + v.w * wq.w;
    }
#pragma unroll
    for (int off = 32; off > 0; off >>= 1) {
        sp += __shfl_xor(sp, off);
        sq += __shfl_xor(sq, off);
    }
    if (lane == 0) { p[n] = sp; q[n] = sq; }
}

// ---------- edge pipeline (e recomputed per pass; no edge-value arrays) ----------
__global__ void edge_max_kernel(const int* __restrict__ src, const int* __restrict__ dst,
                                const float* __restrict__ p, const float* __restrict__ q,
                                const float* __restrict__ bp, unsigned* __restrict__ maxu) {
    int i = blockIdx.x * blockDim.x + threadIdx.x;
    if (i >= Ee) return;
    float v = p[src[i]] + q[dst[i]] + bp[0];
    atomicMax(&maxu[dst[i]], fmap(v));
}
__global__ void edge_den_kernel(const int* __restrict__ src, const int* __restrict__ dst,
                                const float* __restrict__ p, const float* __restrict__ q,
                                const float* __restrict__ bp, const unsigned* __restrict__ maxu,
                                double* __restrict__ den) {
    int i = blockIdx.x * blockDim.x + threadIdx.x;
    if (i >= Ee) return;
    float v = p[src[i]] + q[dst[i]] + bp[0];
    atomicAdd(&den[dst[i]], (double)expf(v - funmap(maxu[dst[i]])));
}
// packed u64 = score(31b) | inv_local_idx(13b) | s_local(10b) | d_local(10b)
__global__ void edge_pack_kernel(const int* __restrict__ src, const int* __restrict__ dst,
                                 const float* __restrict__ p, const float* __restrict__ q,
                                 const float* __restrict__ bp, const unsigned* __restrict__ maxu,
                                 const double* __restrict__ den,
                                 unsigned long long* __restrict__ packed) {
    int i = blockIdx.x * blockDim.x + threadIdx.x;
    if (i >= Ee) return;
    int gs = src[i], gd = dst[i];
    float v = p[gs] + q[gd] + bp[0];
    float sc = expf(v - funmap(maxu[gd])) / (float)den[gd] + 0.5f;   // sc > 0 -> sign bit 0
    int gg = i / EPg;
    unsigned le = (unsigned)(i - gg * EPg);
    unsigned s = (unsigned)(gs - gg * NPg), d = (unsigned)(gd - gg * NPg);
    packed[i] = ((unsigned long long)__float_as_uint(sc) << 33)
              | ((unsigned long long)(8191u - le) << 20)
              | ((unsigned long long)s << 10) | (unsigned long long)d;
}

// ---------- per-graph greedy matching (iterated locally-dominant), LDS-resident ----------
// scal[2] = global cluster counter (final value = num_clusters Cv)
__global__ __launch_bounds__(1024) void match_local_kernel(
        const unsigned long long* __restrict__ packed,
        int* __restrict__ nodeA, int* __restrict__ nodeB,
        float* __restrict__ multc, int* __restrict__ cbatch,
        int* __restrict__ scal) {
    __shared__ unsigned long long best[NPg];      // 8 KB
    __shared__ int mergedS[NPg];                  // 4 KB
    __shared__ unsigned short lst[2][EPg];        // 32 KB
    __shared__ int scnt[2];
    const int g = blockIdx.x;
    const int tid = threadIdx.x;
    const int e0 = g * EPg, n0 = g * NPg;
    for (int i = tid; i < NPg; i += 1024) mergedS[i] = 0;
    for (int i = tid; i < EPg; i += 1024) lst[0][i] = (unsigned short)i;
    if (tid == 0) { scnt[0] = EPg; scnt[1] = 0; }
    __syncthreads();
    int cur = 0;
    for (int round = 0; round < 20000; ++round) {
        const int n_cur = scnt[cur];
        if (n_cur == 0) break;
        if (tid == 0) scnt[cur ^ 1] = 0;
        for (int i = tid; i < NPg; i += 1024) best[i] = 0ull;
        __syncthreads();
        // pass 1: drop dead edges, locally-dominant bid via LDS atomicMax
        for (int ii = tid; ii < n_cur; ii += 1024) {
            int le = lst[cur][ii];
            unsigned long long pk = packed[e0 + le];
            int s = (int)((pk >> 10) & 1023), d = (int)(pk & 1023);
            if (mergedS[s] | mergedS[d]) { lst[cur][ii] = 0xFFFF; continue; }
            atomicMax(&best[s], pk);
            atomicMax(&best[d], pk);
        }
        __syncthreads();
        // pass 2: winners merge; losers carry to next round's list
        for (int ii = tid; ii < n_cur; ii += 1024) {
            int le = lst[cur][ii];
            if (le == 0xFFFF) continue;
            unsigned long long pk = packed[e0 + le];
            int s = (int)((pk >> 10) & 1023), d = (int)(pk & 1023);
            if (best[s] == pk && best[d] == pk) {
                int c = atomicAdd(&scal[2], 1);
                nodeA[c] = n0 + s;
                nodeB[c] = (s == d) ? -1 : (n0 + d);
                multc[c] = __uint_as_float((unsigned)(pk >> 33));
                cbatch[c] = g;
                mergedS[s] = 1;
                if (d != s) mergedS[d] = 1;
            } else {
                int pos = atomicAdd(&scnt[cur ^ 1], 1);
                lst[cur ^ 1][pos] = (unsigned short)le;
            }
        }
        __syncthreads();
        cur ^= 1;
    }
    // unmerged singletons
    for (int i = tid; i < NPg; i += 1024) {
        if (!mergedS[i]) {
            int c = atomicAdd(&scal[2], 1);
            nodeA[c] = n0 + i; nodeB[c] = -1; multc[c] = 1.0f; cbatch[c] = g;
        }
    }
}

// ---------- gather clustered rows: Ag[c] = f16(mult[c]*(relu(bn(h[a]))+relu(bn(h[b])))) ----------
__global__ __launch_bounds__(256) void gather_kernel(const float* __restrict__ h,
        const float* __restrict__ a, const float* __restrict__ bb,
        const int* __restrict__ nodeA, const int* __restrict__ nodeB,
        const float* __restrict__ multc, const int* __restrict__ scal,
        _Float16* __restrict__ Ag) {
    int c = blockIdx.x * 4 + (threadIdx.x >> 6);
    if (c >= scal[2]) return;
    const int lane = threadIdx.x & 63;
    int na = nodeA[c], nb = nodeB[c];
    float mu = multc[c];
#pragma unroll
    for (int u = 0; u < 4; ++u) {
        int j = u * 256 + lane * 4;
        const float4 av = *(const float4*)(a + j);
        const float4 bv = *(const float4*)(bb + j);
        float4 v = *(const float4*)(h + (size_t)na * H1 + j);
        v.x = fmaxf(v.x * av.x + bv.x, 0.f);
        v.y = fmaxf(v.y * av.y + bv.y, 0.f);
        v.z = fmaxf(v.z * av.z + bv.z, 0.f);
        v.w = fmaxf(v.w * av.w + bv.w, 0.f);
        if (nb >= 0) {
            float4 w = *(const float4*)(h + (size_t)nb * H1 + j);
            v.x += fmaxf(w.x * av.x + bv.x, 0.f);
            v.y += fmaxf(w.y * av.y + bv.y, 0.f);
            v.z += fmaxf(w.z * av.z + bv.z, 0.f);
            v.w += fmaxf(w.w * av.w + bv.w, 0.f);
        }
        h4 o = { (_Float16)(mu * v.x), (_Float16)(mu * v.y), (_Float16)(mu * v.z), (_Float16)(mu * v.w) };
        *(h4*)(Ag + (size_t)c * H1 + j) = o;
    }
}

// ---------- BN2 + ReLU + per-graph sum pool ----------
__global__ void pool_kernel(const float* __restrict__ C2, const float* __restrict__ a2,
                            const float* __restrict__ bb2, const int* __restrict__ cbatch,
                            const int* __restrict__ scal, float* __restrict__ pool, float* __restrict__ cnt) {
    int Cv = scal[2];
    int c = blockIdx.x;
    if (c >= Cv) return;
    int g = cbatch[c];
    for (int j = threadIdx.x; j < H2; j += blockDim.x) {
        float v = C2[(size_t)c * H2 + j] * a2[j] + bb2[j];
        v = fmaxf(v, 0.f);
        atomicAdd(&pool[g * H2 + j], v);
    }
    if (threadIdx.x == 0) atomicAdd(&cnt[g], 1.0f);
}

// ---------- FC layers ----------
__global__ void fc1_kernel(const float* __restrict__ pool, const float* __restrict__ cnt,
                           const float* __restrict__ Wfc, const float* __restrict__ bfc,
                           float* __restrict__ hid) {
    int g = blockIdx.x;
    int o = threadIdx.x;
    float inv = 1.0f / fmaxf(cnt[g], 1.0f);
    if (o < 200) {
        float s = 0.f;
        for (int j = 0; j < H2; ++j) s += (pool[g * H2 + j] * inv) * Wfc[o * H2 + j];
        hid[g * 200 + o] = fmaxf(s + bfc[o], 0.f);
    }
}
__global__ void fc2_kernel(const float* __restrict__ hid, const float* __restrict__ Wfc1,
                           const float* __restrict__ bfc1, float* __restrict__ out) {
    int idx = threadIdx.x;
    if (idx < Bb * OUTd) {
        int g = idx / OUTd, o = idx % OUTd;
        float s = bfc1[o];
        for (int t = 0; t < 200; ++t) s += hid[g * 200 + t] * Wfc1[o * 200 + t];
        out[idx] = s;
    }
}

extern "C" void kernel_launch(void* const* d_in, const int* in_sizes, int n_in,
                              void* d_out, int out_size, void* d_ws, size_t ws_size,
                              hipStream_t stream) {
    (void)in_sizes; (void)n_in; (void)out_size; (void)ws_size;
    const float* x    = (const float*)d_in[0];
    const int*   ei   = (const int*)d_in[1];
    const float* W1   = (const float*)d_in[3];
    const float* b1   = (const float*)d_in[4];
    const float* g1   = (const float*)d_in[5];
    const float* be1  = (const float*)d_in[6];
    const float* Wp   = (const float*)d_in[7];
    const float* bp   = (const float*)d_in[8];
    const float* W2   = (const float*)d_in[9];
    const float* b2   = (const float*)d_in[10];
    const float* g2   = (const float*)d_in[11];
    const float* be2  = (const float*)d_in[12];
    const float* Wfc  = (const float*)d_in[13];
    const float* bfc  = (const float*)d_in[14];
    const float* Wfc1 = (const float*)d_in[15];
    const float* bfc1 = (const float*)d_in[16];
    const int* srcp = ei;
    const int* dstp = ei + Ee;

    char* w = (char*)d_ws;
    auto take = [&](size_t bytes) -> char* {
        char* r = w;
        w += (bytes + 255) & ~(size_t)255;
        return r;
    };
    // R1: h (f32, phase 1) -> reused as gemm2 output C2 (phase 2; h dead after gather)
    float* h      = (float*)take((size_t)Nn * H1 * 4);          // 204.8 MB
    // R2: xhi|xlo (gemm1 inputs) -> reused as Ag (f16 gathered rows) after matching
    _Float16* xhi = (_Float16*)take((size_t)Nn * Ff * 2);       // 51.2 MB
    _Float16* xlo = (_Float16*)take((size_t)Nn * Ff * 2);       // 51.2 MB
    _Float16* w1h = (_Float16*)take((size_t)H1 * Ff * 2);
    _Float16* w1l = (_Float16*)take((size_t)H1 * Ff * 2);
    _Float16* w2h = (_Float16*)take((size_t)H2 * H1 * 2);
    float* p      = (float*)take((size_t)Nn * 4);
    float* q      = (float*)take((size_t)Nn * 4);
    unsigned* maxu= (unsigned*)take((size_t)Nn * 4);
    double* den   = (double*)take((size_t)Nn * 8);
    unsigned long long* packed = (unsigned long long*)take((size_t)Ee * 8);
    int* nodeA    = (int*)take((size_t)Nn * 4);
    int* nodeB    = (int*)take((size_t)Nn * 4);
    float* multc  = (float*)take((size_t)Nn * 4);
    int* cbatch   = (int*)take((size_t)Nn * 4);
    double* cs1   = (double*)take((size_t)H1 * 8);
    double* css1  = (double*)take((size_t)H1 * 8);
    double* cs2   = (double*)take((size_t)H2 * 8);
    double* css2  = (double*)take((size_t)H2 * 8);
    float* a1     = (float*)take((size_t)H1 * 4);
    float* bb1    = (float*)take((size_t)H1 * 4);
    float* a2     = (float*)take((size_t)H2 * 4);
    float* bb2    = (float*)take((size_t)H2 * 4);
    float* pool   = (float*)take((size_t)Bb * H2 * 4);
    float* cnt    = (float*)take((size_t)Bb * 4);
    float* hid    = (float*)take((size_t)Bb * 200 * 4);
    int* scal     = (int*)take(64 * 4);
    _Float16* Ag  = xhi;   // alias: xhi+xlo (102.4MB) reused for Ag[Nn][H1] after gemm1
    float* C2o    = h;     // alias: h region reused for gemm2 output [Cv][H2] after gather

    const int mT = (Nn + 127) / 128;   // 391

    init_kernel<<<dim3(256), dim3(256), 0, stream>>>(maxu, den, cs1, css1, cs2, css2, pool, cnt, scal);
    split_pair_kernel<<<dim3(2048), dim3(256), 0, stream>>>(x, xhi, xlo, Nn * Ff / 4);
    split_pair_kernel<<<dim3(512), dim3(256), 0, stream>>>(W1, w1h, w1l, H1 * Ff / 4);
    tof16_kernel<<<dim3(512), dim3(256), 0, stream>>>(W2, w2h, H2 * H1 / 4);
    gemm_mfma_kernel<Ff, true><<<dim3(mT * (H1 / 128)), dim3(256), 0, stream>>>(
        xhi, xlo, w1h, w1l, b1, h, H1, Nn, nullptr, H1 / 128, cs1, css1);
    bnparam_kernel<<<dim3((H1 + 255) / 256), dim3(256), 0, stream>>>(cs1, css1, g1, be1, a1, bb1, H1, (const float*)nullptr, (const int*)nullptr);
    pq_kernel<<<dim3((Nn + 3) / 4), dim3(256), 0, stream>>>(h, a1, bb1, Wp, p, q);
    edge_max_kernel<<<dim3((Ee + 255) / 256), dim3(256), 0, stream>>>(srcp, dstp, p, q, bp, maxu);
    edge_den_kernel<<<dim3((Ee + 255) / 256), dim3(256), 0, stream>>>(srcp, dstp, p, q, bp, maxu, den);
    edge_pack_kernel<<<dim3((Ee + 255) / 256), dim3(256), 0, stream>>>(srcp, dstp, p, q, bp, maxu, den, packed);
    match_local_kernel<<<dim3(Bb), dim3(1024), 0, stream>>>(packed, nodeA, nodeB, multc, cbatch, scal);
    gather_kernel<<<dim3((Nn + 3) / 4), dim3(256), 0, stream>>>(h, a1, bb1, nodeA, nodeB, multc, scal, Ag);
    gemm_mfma_kernel<H1, false><<<dim3(mT * (H2 / 128)), dim3(256), 0, stream>>>(
        Ag, nullptr, w2h, nullptr, b2, C2o, H2, 0, scal + 2, H2 / 128, cs2, css2);
    bnparam_kernel<<<dim3((H2 + 255) / 256), dim3(256), 0, stream>>>(cs2, css2, g2, be2, a2, bb2, H2, b2, scal + 2);
    pool_kernel<<<dim3(Nn), dim3(256), 0, stream>>>(C2o, a2, bb2, cbatch, scal, pool, cnt);
    fc1_kernel<<<dim3(Bb), dim3(256), 0, stream>>>(pool, cnt, Wfc, bfc, hid);
    fc2_kernel<<<dim3(1), dim3(512), 0, stream>>>(hid, Wfc1, bfc1, (float*)d_out);
}

// Round 10
// 699.751 us; speedup vs baseline: 1.3172x; 1.3172x over previous
//
#include <hip/hip_runtime.h>

#define Nn   50000
#define Ee   400000
#define Ff   512
#define H1   1024
#define H2   512
#define Bb   50
#define OUTd 10
#define EPSc 1e-5f
#define NPg  1000   // nodes per graph
#define EPg  8000   // edges per graph

typedef _Float16 h8 __attribute__((ext_vector_type(8)));
typedef _Float16 h4 __attribute__((ext_vector_type(4)));
typedef float f4 __attribute__((ext_vector_type(4)));

// ---------- monotone float<->uint mapping for atomicMax on floats ----------
__device__ __forceinline__ unsigned fmap(float f) {
    unsigned u = __float_as_uint(f);
    return (u & 0x80000000u) ? ~u : (u | 0x80000000u);
}
__device__ __forceinline__ float funmap(unsigned m) {
    unsigned u = (m & 0x80000000u) ? (m ^ 0x80000000u) : ~m;
    return __uint_as_float(u);
}

__device__ __forceinline__ void gl_lds16(const void* g, void* l) {
    __builtin_amdgcn_global_load_lds(
        (const __attribute__((address_space(1))) unsigned int*)g,
        (__attribute__((address_space(3))) unsigned int*)l,
        16, 0, 0);
}

// ---------- init: zero accumulators (ws is poisoned 0xAA once) ----------
__global__ void init_kernel(double* cs1, double* css1, double* cs2, double* css2, int* scal) {
    int i = blockIdx.x * blockDim.x + threadIdx.x;
    int nth = gridDim.x * blockDim.x;
    for (int j = i; j < H1; j += nth) { cs1[j] = 0.0; css1[j] = 0.0; }
    for (int j = i; j < H2; j += nth) { cs2[j] = 0.0; css2[j] = 0.0; }
    if (i < 16) scal[i] = 0;
}

// ---------- f32 -> f16 hi/lo split (compensated) ----------
__global__ void split_pair_kernel(const float* __restrict__ in, _Float16* __restrict__ hi,
                                  _Float16* __restrict__ lo, int n4) {
    int i = blockIdx.x * blockDim.x + threadIdx.x;
    int nth = gridDim.x * blockDim.x;
    for (; i < n4; i += nth) {
        float4 v = ((const float4*)in)[i];
        h4 H = { (_Float16)v.x, (_Float16)v.y, (_Float16)v.z, (_Float16)v.w };
        h4 L = { (_Float16)(v.x - (float)H[0]), (_Float16)(v.y - (float)H[1]),
                 (_Float16)(v.z - (float)H[2]), (_Float16)(v.w - (float)H[3]) };
        ((h4*)hi)[i] = H;
        ((h4*)lo)[i] = L;
    }
}
// ---------- f32 -> f16 single ----------
__global__ void tof16_kernel(const float* __restrict__ in, _Float16* __restrict__ out, int n4) {
    int i = blockIdx.x * blockDim.x + threadIdx.x;
    int nth = gridDim.x * blockDim.x;
    for (; i < n4; i += nth) {
        float4 v = ((const float4*)in)[i];
        h4 H = { (_Float16)v.x, (_Float16)v.y, (_Float16)v.z, (_Float16)v.w };
        ((h4*)out)[i] = H;
    }
}

// ---------- MFMA GEMM (round-7 proven schedule): 128x128 tile, BK=32, 4 waves,
// double-buffered staging, ONE barrier per K-step; XCD-chunk bijective swizzle;
// LDS granule swizzle (conflict-free). SPLIT: C = Ahi*Bhi + Ahi*Blo + Alo*Bhi.
template<int KD, bool SPLIT>
__global__ __launch_bounds__(256) void gemm_mfma_kernel(
        const _Float16* __restrict__ Ahi, const _Float16* __restrict__ Alo,
        const _Float16* __restrict__ Bhi, const _Float16* __restrict__ Blo,
        const float* __restrict__ bias, float* __restrict__ C, int Nc,
        int Mconst, const int* __restrict__ Mptr, int nT,
        double* __restrict__ csum, double* __restrict__ cssum)
{
    const int M = Mptr ? Mptr[0] : Mconst;
    const int nwg = gridDim.x, orig = blockIdx.x;
    const int qq = nwg >> 3, rr = nwg & 7;
    const int xcd = orig & 7, idx = orig >> 3;
    const int lin = (xcd < rr ? xcd * (qq + 1) : rr * (qq + 1) + (xcd - rr) * qq) + idx;
    const int bmI = lin / nT;
    const int bm = bmI * 128, bn = (lin - bmI * nT) * 128;
    if (bm >= M) return;
    constexpr int NARR = SPLIT ? 4 : 2;
    __shared__ __align__(16) _Float16 smem[2][NARR][128 * 32];
    const int tid = threadIdx.x, lane = tid & 63, wave = tid >> 6;
    const int rIn = lane >> 2;
    const int kSrcByte = ((((lane & 3) - ((lane >> 3) & 3)) & 3) << 4);
    const int wr = wave >> 1, wc = wave & 1;
    const int lr = lane & 15, kb = lane >> 4;
    const int pGr = ((kb + ((lr >> 1) & 3)) & 3) << 3;
    f4 acc[4][4] = {};

    auto STAGE = [&](int b, int k0) {
        if (SPLIT) {
            const _Float16* gp = (wave == 0) ? Ahi : (wave == 1) ? Alo : (wave == 2) ? Bhi : Blo;
            _Float16* lp = smem[b][wave];
            const bool isA = (wave < 2);
            const int tb = isA ? bm : bn;
#pragma unroll
            for (int c = 0; c < 8; ++c) {
                int row = tb + c * 16 + rIn;
                if (isA) row = min(row, M - 1);
                gl_lds16((const char*)gp + ((size_t)row * KD + k0) * 2 + kSrcByte, lp + c * 512);
            }
        } else {
            const bool isA = (wave < 2);
            const _Float16* gp = isA ? Ahi : Bhi;
            _Float16* lp = smem[b][isA ? 0 : 1];
            const int tb = isA ? bm : bn;
            const int hf = wave & 1;
#pragma unroll
            for (int c2 = 0; c2 < 4; ++c2) {
                int c = hf * 4 + c2;
                int row = tb + c * 16 + rIn;
                if (isA) row = min(row, M - 1);
                gl_lds16((const char*)gp + ((size_t)row * KD + k0) * 2 + kSrcByte, lp + c * 512);
            }
        }
    };

    int cur = 0;
    STAGE(0, 0);
    for (int k0 = 0; k0 < KD; k0 += 32) {
        __syncthreads();
        if (k0 + 32 < KD) STAGE(cur ^ 1, k0 + 32);
        const _Float16* AhP = smem[cur][0];
        const _Float16* AlP = SPLIT ? smem[cur][1] : nullptr;
        const _Float16* BhP = SPLIT ? smem[cur][2] : smem[cur][1];
        const _Float16* BlP = SPLIT ? smem[cur][3] : nullptr;
        const int ar = (wr * 64 + lr) * 32 + pGr;
        const int br = (wc * 64 + lr) * 32 + pGr;
        h8 ahf[4], bhf[4], alf[4], blf[4];
#pragma unroll
        for (int i = 0; i < 4; ++i) {
            ahf[i] = *(const h8*)&AhP[ar + i * 512];
            bhf[i] = *(const h8*)&BhP[br + i * 512];
            if (SPLIT) {
                alf[i] = *(const h8*)&AlP[ar + i * 512];
                blf[i] = *(const h8*)&BlP[br + i * 512];
            }
        }
#pragma unroll
        for (int mi = 0; mi < 4; ++mi)
#pragma unroll
            for (int ni = 0; ni < 4; ++ni) {
                acc[mi][ni] = __builtin_amdgcn_mfma_f32_16x16x32_f16(ahf[mi], bhf[ni], acc[mi][ni], 0, 0, 0);
                if (SPLIT) {
                    acc[mi][ni] = __builtin_amdgcn_mfma_f32_16x16x32_f16(ahf[mi], blf[ni], acc[mi][ni], 0, 0, 0);
                    acc[mi][ni] = __builtin_amdgcn_mfma_f32_16x16x32_f16(alf[mi], bhf[ni], acc[mi][ni], 0, 0, 0);
                }
            }
        cur ^= 1;
    }
    // epilogue: bias, store, fused column stats. C/D map: col=lane&15, row=(lane>>4)*4+reg
#pragma unroll
    for (int ni = 0; ni < 4; ++ni) {
        const int col = bn + wc * 64 + ni * 16 + lr;
        const float bv = bias[col];
        double sd_ = 0.0, ssd = 0.0;
#pragma unroll
        for (int mi = 0; mi < 4; ++mi)
#pragma unroll
            for (int r = 0; r < 4; ++r) {
                int row = bm + wr * 64 + mi * 16 + kb * 4 + r;
                if (row < M) {
                    float v = acc[mi][ni][r] + bv;
                    C[(size_t)row * Nc + col] = v;
                    sd_ += (double)v;
                    ssd += (double)v * (double)v;
                }
            }
        sd_ += __shfl_xor(sd_, 16); ssd += __shfl_xor(ssd, 16);
        sd_ += __shfl_xor(sd_, 32); ssd += __shfl_xor(ssd, 32);
        if (kb == 0) {
            atomicAdd(&csum[col], sd_);
            atomicAdd(&cssum[col], ssd);
        }
    }
}

// ---------- BN params ----------
__global__ void bnparam_kernel(const double* __restrict__ s, const double* __restrict__ ss,
                               const float* __restrict__ g, const float* __restrict__ be,
                               float* __restrict__ a, float* __restrict__ bb, int cols,
                               const float* __restrict__ padBias, const int* __restrict__ CvPtr) {
    int j = blockIdx.x * blockDim.x + threadIdx.x;
    if (j >= cols) return;
    double sum = s[j], sumsq = ss[j];
    if (CvPtr) {
        double pad = (double)(Nn - CvPtr[0]);
        double bv = padBias ? (double)padBias[j] : 0.0;
        sum += pad * bv; sumsq += pad * bv * bv;
    }
    double mean = sum / (double)Nn;
    double var = sumsq / (double)Nn - mean * mean;
    float aj = g[j] / sqrtf((float)var + EPSc);
    a[j] = aj;
    bb[j] = be[j] - (float)mean * aj;
}

// ---------- p,q row dots over BN+ReLU(h), no write-back; one WAVE per node ----------
__global__ __launch_bounds__(256) void pq_kernel(const float* __restrict__ h,
        const float* __restrict__ a, const float* __restrict__ bb,
        const float* __restrict__ Wp, float* __restrict__ p, float* __restrict__ q) {
    const int n = blockIdx.x * 4 + (threadIdx.x >> 6);
    if (n >= Nn) return;
    const int lane = threadIdx.x & 63;
    float sp = 0.f, sq = 0.f;
    const float* row = h + (size_t)n * H1;
#pragma unroll
    for (int u = 0; u < 4; ++u) {
        int j = u * 256 + lane * 4;
        float4 v = *(const float4*)(row + j);
        const float4 av = *(const float4*)(a + j);
        const float4 bv = *(const float4*)(bb + j);
        v.x = fmaxf(v.x * av.x + bv.x, 0.f);
        v.y = fmaxf(v.y * av.y + bv.y, 0.f);
        v.z = fmaxf(v.z * av.z + bv.z, 0.f);
        v.w = fmaxf(v.w * av.w + bv.w, 0.f);
        const float4 wp = *(const float4*)(Wp + j);
        const float4 wq = *(const float4*)(Wp + H1 + j);
        sp += v.x * wp.x + v.y * wp.y + v.z * wp.z + v.w * wp.w;
        sq += v.x * wq.x + v.y * wq.y + v.z * wq.z + v.w * wq.w;
    }
#pragma unroll
    for (int off = 32; off > 0; off >>= 1) {
        sp += __shfl_xor(sp, off);
        sq += __shfl_xor(sq, off);
    }
    if (lane == 0) { p[n] = sp; q[n] = sq; }
}

// ---------- fused edge-score + greedy matching, one block per graph ----------
// LDS (52KB, overlaid phases):
//   [0..32000)    earr f32[8000]  -> lst u16[2][8000]
//   [32000..40000) pl,ql f32[1000] -> best u64[1000]
//   [40000..44000) maxu u32[1000] -> mergedS i32[1000]
//   [44000..52000) den u64[1000]  -> lmult f32[1000] + lsA,ldA u16[1000]
// scal[2] = global cluster counter; gbase/gcnt = per-graph segment table.
__global__ __launch_bounds__(1024) void match_fused_kernel(
        const int* __restrict__ ei,
        const float* __restrict__ p, const float* __restrict__ q,
        const float* __restrict__ bp,
        unsigned long long* __restrict__ packed,
        int* __restrict__ nodeA, int* __restrict__ nodeB,
        float* __restrict__ multc, int* __restrict__ scal,
        int* __restrict__ gbase, int* __restrict__ gcnt) {
    __shared__ __align__(16) char LB[52096];
    unsigned short* lst = (unsigned short*)LB;            // [2][8000]
    float* earr = (float*)LB;
    float* pl = (float*)(LB + 32000);
    float* ql = pl + NPg;
    unsigned long long* best = (unsigned long long*)(LB + 32000);
    unsigned* maxu = (unsigned*)(LB + 40000);
    int* mergedS = (int*)(LB + 40000);
    unsigned long long* den = (unsigned long long*)(LB + 44000);
    float* lmult = (float*)(LB + 44000);
    unsigned short* lsA = (unsigned short*)(LB + 48000);
    unsigned short* ldA = (unsigned short*)(LB + 50000);
    int* cnts = (int*)(LB + 52032);                       // [0]=scnt0 [1]=scnt1 [2]=ncl [3]=base

    const int g = blockIdx.x;
    const int tid = threadIdx.x;
    const int e0 = g * EPg, n0 = g * NPg;
    const int* srcp = ei + e0;
    const int* dstp = ei + Ee + e0;
    const float bpv = bp[0];

    for (int i = tid; i < NPg; i += 1024) {
        pl[i] = p[n0 + i];
        ql[i] = q[n0 + i];
        maxu[i] = 0u;
        den[i] = 0ull;
    }
    __syncthreads();
    // pass A: e + segment max (exact, same float ordering as before)
    for (int i = tid; i < EPg; i += 1024) {
        int s = srcp[i] - n0, d = dstp[i] - n0;
        float e = pl[s] + ql[d] + bpv;
        earr[i] = e;
        atomicMax(&maxu[d], fmap(e));
    }
    __syncthreads();
    // pass B: fixed-point denominator (deterministic; <=2e-7 rel vs f64 path)
    for (int i = tid; i < EPg; i += 1024) {
        int d = dstp[i] - n0;
        float ex = expf(earr[i] - funmap(maxu[d]));
        atomicAdd(&den[d], (unsigned long long)(ex * 4294967296.0f));
    }
    __syncthreads();
    // pass C: score -> packed u64 = score(31b)|inv_idx(13b)|s(10b)|d(10b)
    for (int i = tid; i < EPg; i += 1024) {
        int s = srcp[i] - n0, d = dstp[i] - n0;
        float ex = expf(earr[i] - funmap(maxu[d]));
        float den_f = (float)((double)den[d] * (1.0 / 4294967296.0));
        float sc = ex / den_f + 0.5f;
        packed[e0 + i] = ((unsigned long long)__float_as_uint(sc) << 33)
                       | ((unsigned long long)(8191u - (unsigned)i) << 20)
                       | ((unsigned long long)(unsigned)s << 10) | (unsigned long long)(unsigned)d;
    }
    __syncthreads();
    // init matching state (overlays now safe)
    for (int i = tid; i < NPg; i += 1024) mergedS[i] = 0;
    for (int i = tid; i < EPg; i += 1024) lst[i] = (unsigned short)i;   // lst[0][i]
    if (tid == 0) { cnts[0] = EPg; cnts[1] = 0; cnts[2] = 0; }
    __syncthreads();
    int cur = 0;
    for (int round = 0; round < 20000; ++round) {
        const int n_cur = cnts[cur];
        if (n_cur == 0) break;
        if (tid == 0) cnts[cur ^ 1] = 0;
        for (int i = tid; i < NPg; i += 1024) best[i] = 0ull;
        __syncthreads();
        for (int ii = tid; ii < n_cur; ii += 1024) {
            int le = lst[cur * EPg + ii];
            unsigned long long pk = packed[e0 + le];
            int s = (int)((pk >> 10) & 1023), d = (int)(pk & 1023);
            if (mergedS[s] | mergedS[d]) { lst[cur * EPg + ii] = 0xFFFF; continue; }
            atomicMax(&best[s], pk);
            atomicMax(&best[d], pk);
        }
        __syncthreads();
        for (int ii = tid; ii < n_cur; ii += 1024) {
            int le = lst[cur * EPg + ii];
            if (le == 0xFFFF) continue;
            unsigned long long pk = packed[e0 + le];
            int s = (int)((pk >> 10) & 1023), d = (int)(pk & 1023);
            if (best[s] == pk && best[d] == pk) {
                int c = atomicAdd(&cnts[2], 1);
                lsA[c] = (unsigned short)s;
                ldA[c] = (s == d) ? (unsigned short)0xFFFF : (unsigned short)d;
                lmult[c] = __uint_as_float((unsigned)(pk >> 33));
                mergedS[s] = 1;
                if (d != s) mergedS[d] = 1;
            } else {
                int pos = atomicAdd(&cnts[cur ^ 1], 1);
                lst[(cur ^ 1) * EPg + pos] = (unsigned short)le;
            }
        }
        __syncthreads();
        cur ^= 1;
    }
    // singletons
    for (int i = tid; i < NPg; i += 1024) {
        if (!mergedS[i]) {
            int c = atomicAdd(&cnts[2], 1);
            lsA[c] = (unsigned short)i;
            ldA[c] = 0xFFFF;
            lmult[c] = 1.0f;
        }
    }
    __syncthreads();
    if (tid == 0) {
        int ncl = cnts[2];
        int base = atomicAdd(&scal[2], ncl);
        cnts[3] = base;
        gbase[g] = base;
        gcnt[g] = ncl;
    }
    __syncthreads();
    const int ncl = cnts[2], base = cnts[3];
    for (int i = tid; i < ncl; i += 1024) {
        nodeA[base + i] = n0 + (int)lsA[i];
        nodeB[base + i] = (ldA[i] == 0xFFFF) ? -1 : (n0 + (int)ldA[i]);
        multc[base + i] = lmult[i];
    }
}

// ---------- gather clustered rows: Ag[c] = f16(mult*(relu(bn(h[a]))+relu(bn(h[b])))) ----------
__global__ __launch_bounds__(256) void gather_kernel(const float* __restrict__ h,
        const float* __restrict__ a, const float* __restrict__ bb,
        const int* __restrict__ nodeA, const int* __restrict__ nodeB,
        const float* __restrict__ multc, const int* __restrict__ scal,
        _Float16* __restrict__ Ag) {
    int c = blockIdx.x * 4 + (threadIdx.x >> 6);
    if (c >= scal[2]) return;
    const int lane = threadIdx.x & 63;
    int na = nodeA[c], nb = nodeB[c];
    float mu = multc[c];
#pragma unroll
    for (int u = 0; u < 4; ++u) {
        int j = u * 256 + lane * 4;
        const float4 av = *(const float4*)(a + j);
        const float4 bv = *(const float4*)(bb + j);
        float4 v = *(const float4*)(h + (size_t)na * H1 + j);
        v.x = fmaxf(v.x * av.x + bv.x, 0.f);
        v.y = fmaxf(v.y * av.y + bv.y, 0.f);
        v.z = fmaxf(v.z * av.z + bv.z, 0.f);
        v.w = fmaxf(v.w * av.w + bv.w, 0.f);
        if (nb >= 0) {
            float4 w = *(const float4*)(h + (size_t)nb * H1 + j);
            v.x += fmaxf(w.x * av.x + bv.x, 0.f);
            v.y += fmaxf(w.y * av.y + bv.y, 0.f);
            v.z += fmaxf(w.z * av.z + bv.z, 0.f);
            v.w += fmaxf(w.w * av.w + bv.w, 0.f);
        }
        h4 o = { (_Float16)(mu * v.x), (_Float16)(mu * v.y), (_Float16)(mu * v.z), (_Float16)(mu * v.w) };
        *(h4*)(Ag + (size_t)c * H1 + j) = o;
    }
}

// ---------- BN2+ReLU+per-graph sum pool over contiguous segments (no atomics) ----------
__global__ __launch_bounds__(256) void pool_seg_kernel(const float* __restrict__ C2,
        const float* __restrict__ a2, const float* __restrict__ bb2,
        const int* __restrict__ gbase, const int* __restrict__ gcnt,
        float* __restrict__ pool) {
    const int g = blockIdx.x;
    const int j = blockIdx.y * 256 + threadIdx.x;
    const int b0 = gbase[g], cN = gcnt[g];
    const float aj = a2[j], bj = bb2[j];
    float s = 0.f;
    for (int c = b0; c < b0 + cN; ++c)
        s += fmaxf(C2[(size_t)c * H2 + j] * aj + bj, 0.f);
    pool[g * H2 + j] = s;
}

// ---------- FC layers ----------
__global__ void fc1_kernel(const float* __restrict__ pool, const int* __restrict__ gcnt,
                           const float* __restrict__ Wfc, const float* __restrict__ bfc,
                           float* __restrict__ hid) {
    int g = blockIdx.x;
    int o = threadIdx.x;
    float inv = 1.0f / fmaxf((float)gcnt[g], 1.0f);
    if (o < 200) {
        float s = 0.f;
        for (int j = 0; j < H2; ++j) s += (pool[g * H2 + j] * inv) * Wfc[o * H2 + j];
        hid[g * 200 + o] = fmaxf(s + bfc[o], 0.f);
    }
}
__global__ void fc2_kernel(const float* __restrict__ hid, const float* __restrict__ Wfc1,
                           const float* __restrict__ bfc1, float* __restrict__ out) {
    int idx = threadIdx.x;
    if (idx < Bb * OUTd) {
        int g = idx / OUTd, o = idx % OUTd;
        float s = bfc1[o];
        for (int t = 0; t < 200; ++t) s += hid[g * 200 + t] * Wfc1[o * 200 + t];
        out[idx] = s;
    }
}

extern "C" void kernel_launch(void* const* d_in, const int* in_sizes, int n_in,
                              void* d_out, int out_size, void* d_ws, size_t ws_size,
                              hipStream_t stream) {
    (void)in_sizes; (void)n_in; (void)out_size; (void)ws_size;
    const float* x    = (const float*)d_in[0];
    const int*   ei   = (const int*)d_in[1];
    const float* W1   = (const float*)d_in[3];
    const float* b1   = (const float*)d_in[4];
    const float* g1   = (const float*)d_in[5];
    const float* be1  = (const float*)d_in[6];
    const float* Wp   = (const float*)d_in[7];
    const float* bp   = (const float*)d_in[8];
    const float* W2   = (const float*)d_in[9];
    const float* b2   = (const float*)d_in[10];
    const float* g2   = (const float*)d_in[11];
    const float* be2  = (const float*)d_in[12];
    const float* Wfc  = (const float*)d_in[13];
    const float* bfc  = (const float*)d_in[14];
    const float* Wfc1 = (const float*)d_in[15];
    const float* bfc1 = (const float*)d_in[16];

    char* w = (char*)d_ws;
    auto take = [&](size_t bytes) -> char* {
        char* r = w;
        w += (bytes + 255) & ~(size_t)255;
        return r;
    };
    // R1: h (f32) -> reused as gemm2 output C2 after gather
    float* h      = (float*)take((size_t)Nn * H1 * 4);          // 204.8 MB
    // R2: xhi|xlo -> reused as Ag (f16 gathered rows) after matching
    _Float16* xhi = (_Float16*)take((size_t)Nn * Ff * 2);       // 51.2 MB
    _Float16* xlo = (_Float16*)take((size_t)Nn * Ff * 2);       // 51.2 MB
    _Float16* w1h = (_Float16*)take((size_t)H1 * Ff * 2);
    _Float16* w1l = (_Float16*)take((size_t)H1 * Ff * 2);
    _Float16* w2h = (_Float16*)take((size_t)H2 * H1 * 2);
    float* p      = (float*)take((size_t)Nn * 4);
    float* q      = (float*)take((size_t)Nn * 4);
    unsigned long long* packed = (unsigned long long*)take((size_t)Ee * 8);
    int* nodeA    = (int*)take((size_t)Nn * 4);
    int* nodeB    = (int*)take((size_t)Nn * 4);
    float* multc  = (float*)take((size_t)Nn * 4);
    double* cs1   = (double*)take((size_t)H1 * 8);
    double* css1  = (double*)take((size_t)H1 * 8);
    double* cs2   = (double*)take((size_t)H2 * 8);
    double* css2  = (double*)take((size_t)H2 * 8);
    float* a1     = (float*)take((size_t)H1 * 4);
    float* bb1    = (float*)take((size_t)H1 * 4);
    float* a2     = (float*)take((size_t)H2 * 4);
    float* bb2    = (float*)take((size_t)H2 * 4);
    float* pool   = (float*)take((size_t)Bb * H2 * 4);
    float* hid    = (float*)take((size_t)Bb * 200 * 4);
    int* scal     = (int*)take(64 * 4);
    int* gbase    = (int*)take(64 * 4);
    int* gcnt     = (int*)take(64 * 4);
    _Float16* Ag  = xhi;   // alias after gemm1
    float* C2o    = h;     // alias after gather

    const int mT = (Nn + 127) / 128;   // 391

    init_kernel<<<dim3(16), dim3(256), 0, stream>>>(cs1, css1, cs2, css2, scal);
    split_pair_kernel<<<dim3(2048), dim3(256), 0, stream>>>(x, xhi, xlo, Nn * Ff / 4);
    split_pair_kernel<<<dim3(512), dim3(256), 0, stream>>>(W1, w1h, w1l, H1 * Ff / 4);
    tof16_kernel<<<dim3(512), dim3(256), 0, stream>>>(W2, w2h, H2 * H1 / 4);
    gemm_mfma_kernel<Ff, true><<<dim3(mT * (H1 / 128)), dim3(256), 0, stream>>>(
        xhi, xlo, w1h, w1l, b1, h, H1, Nn, nullptr, H1 / 128, cs1, css1);
    bnparam_kernel<<<dim3((H1 + 255) / 256), dim3(256), 0, stream>>>(cs1, css1, g1, be1, a1, bb1, H1, (const float*)nullptr, (const int*)nullptr);
    pq_kernel<<<dim3((Nn + 3) / 4), dim3(256), 0, stream>>>(h, a1, bb1, Wp, p, q);
    match_fused_kernel<<<dim3(Bb), dim3(1024), 0, stream>>>(ei, p, q, bp, packed,
        nodeA, nodeB, multc, scal, gbase, gcnt);
    gather_kernel<<<dim3((Nn + 3) / 4), dim3(256), 0, stream>>>(h, a1, bb1, nodeA, nodeB, multc, scal, Ag);
    gemm_mfma_kernel<H1, false><<<dim3(mT * (H2 / 128)), dim3(256), 0, stream>>>(
        Ag, nullptr, w2h, nullptr, b2, C2o, H2, 0, scal + 2, H2 / 128, cs2, css2);
    bnparam_kernel<<<dim3((H2 + 255) / 256), dim3(256), 0, stream>>>(cs2, css2, g2, be2, a2, bb2, H2, b2, scal + 2);
    pool_seg_kernel<<<dim3(Bb, H2 / 256), dim3(256), 0, stream>>>(C2o, a2, bb2, gbase, gcnt, pool);
    fc1_kernel<<<dim3(Bb), dim3(256), 0, stream>>>(pool, gcnt, Wfc, bfc, hid);
    fc2_kernel<<<dim3(1), dim3(512), 0, stream>>>(hid, Wfc1, bfc1, (float*)d_out);
}